// Round 2
// baseline (171.865 us; speedup 1.0000x reference)
//
#include <hip/hip_runtime.h>
#include <stdint.h>

#define N_DIM 4096
#define B_DIM 64

typedef __bf16 bf16x8 __attribute__((ext_vector_type(8)));
typedef float floatx4 __attribute__((ext_vector_type(4)));

union FragU { uint4 u; bf16x8 h; };

__device__ __forceinline__ unsigned short f2bf_rne(float f) {
    unsigned int u = __float_as_uint(f);
    u += 0x7fffu + ((u >> 16) & 1u);
    return (unsigned short)(u >> 16);
}

// c = Vmag*cos(ang), s = Vmag*sin(ang).
// fp32 copies in natural [b][j] layout (for epilogue),
// bf16 copies packed in MFMA B-fragment order: idx = ((j>>3)*64 + b)*8 + (j&7)
__global__ __launch_bounds__(256) void pf_prep(
        const float* __restrict__ Vmag, const float* __restrict__ Vang,
        unsigned short* __restrict__ c_pk, unsigned short* __restrict__ s_pk,
        float* __restrict__ c_f, float* __restrict__ s_f) {
    int idx = blockIdx.x * 256 + threadIdx.x;   // = b*4096 + j
    int b = idx >> 12;
    int j = idx & 4095;
    float sv, cv;
    sincosf(Vang[idx], &sv, &cv);
    float v = Vmag[idx];
    float c = v * cv;
    float s = v * sv;
    c_f[idx] = c;
    s_f[idx] = s;
    int p = (((j >> 3) << 6) + b) * 8 + (j & 7);
    c_pk[p] = f2bf_rne(c);
    s_pk[p] = f2bf_rne(s);
}

// One workgroup = 16 rows (i) of G/B, 64 batches, 16 waves split K=4096 into
// 256-element chunks (8 iters of K=32). Wave tile: 16i x 64b, X and Y accs.
// X = G*c + B*s ; Y = G*s - B*c  (the -c via sign-bit XOR on the bf16 frag)
// A (G/B) operands software-pipelined one iteration ahead (HBM latency);
// c/s fragments read from L2 each iter, covered by 4 waves/SIMD interleave.
__global__ __launch_bounds__(1024, 4) void pf_gemm(
        const float* __restrict__ G, const float* __restrict__ Bm,
        const unsigned short* __restrict__ c_pk, const unsigned short* __restrict__ s_pk,
        const float* __restrict__ c_f, const float* __restrict__ s_f,
        const float* __restrict__ P_in, const float* __restrict__ Q_in,
        float* __restrict__ out) {
    __shared__ float red[2][8][16][66];   // [X/Y][wavepair][m][b] (pad 66 -> <=2-way)
    const int tid = threadIdx.x;
    const int wave = tid >> 6;        // 0..15
    const int lane = tid & 63;
    const int n = lane & 15;          // A: row index m ; B: col index b
    const int quad = lane >> 4;       // selects k-subgroup of 8
    const int i0 = blockIdx.x << 4;   // 16 rows per workgroup
    const int kw = wave << 8;         // wave's K-chunk start (256 per wave)

    // A operand: G[i0+n][k], k = kw + quad*8 + (0..7), 8 contiguous fp32
    const float* gp = G  + (size_t)(i0 + n) * N_DIM + kw + (quad << 3);
    const float* bp = Bm + (size_t)(i0 + n) * N_DIM + kw + (quad << 3);
    // B operand: packed bf16, 8 contiguous per lane
    const unsigned short* cp = c_pk + ((size_t)(((kw >> 3) + quad) << 6) + n) * 8;
    const unsigned short* sp = s_pk + ((size_t)(((kw >> 3) + quad) << 6) + n) * 8;

    floatx4 accX[4], accY[4];
    #pragma unroll
    for (int t = 0; t < 4; ++t) {
        accX[t] = (floatx4){0.f, 0.f, 0.f, 0.f};
        accY[t] = (floatx4){0.f, 0.f, 0.f, 0.f};
    }

    // preload iteration 0's A operands
    float4 g0 = *(const float4*)gp;
    float4 g1 = *(const float4*)(gp + 4);
    float4 h0 = *(const float4*)bp;
    float4 h1 = *(const float4*)(bp + 4);
    gp += 32; bp += 32;

    #pragma unroll 1
    for (int it = 0; it < 8; ++it) {
        float4 ng0, ng1, nh0, nh1;
        if (it < 7) {                         // prefetch next iter's A (stays in flight)
            ng0 = *(const float4*)gp;
            ng1 = *(const float4*)(gp + 4);
            nh0 = *(const float4*)bp;
            nh1 = *(const float4*)(bp + 4);
            gp += 32; bp += 32;
        }

        uint4 cu[4];
        #pragma unroll
        for (int t = 0; t < 4; ++t) cu[t] = *(const uint4*)(cp + t * 128);
        cp += 2048;

        bf16x8 ag, ah;
        ag[0] = (__bf16)g0.x; ag[1] = (__bf16)g0.y; ag[2] = (__bf16)g0.z; ag[3] = (__bf16)g0.w;
        ag[4] = (__bf16)g1.x; ag[5] = (__bf16)g1.y; ag[6] = (__bf16)g1.z; ag[7] = (__bf16)g1.w;
        ah[0] = (__bf16)h0.x; ah[1] = (__bf16)h0.y; ah[2] = (__bf16)h0.z; ah[3] = (__bf16)h0.w;
        ah[4] = (__bf16)h1.x; ah[5] = (__bf16)h1.y; ah[6] = (__bf16)h1.z; ah[7] = (__bf16)h1.w;

        // c-phase: X += G*c ; Y += B*(-c)
        #pragma unroll
        for (int t = 0; t < 4; ++t) {
            FragU cf, nf;
            cf.u = cu[t];
            nf.u.x = cu[t].x ^ 0x80008000u;
            nf.u.y = cu[t].y ^ 0x80008000u;
            nf.u.z = cu[t].z ^ 0x80008000u;
            nf.u.w = cu[t].w ^ 0x80008000u;
            accX[t] = __builtin_amdgcn_mfma_f32_16x16x32_bf16(ag, cf.h, accX[t], 0, 0, 0);
            accY[t] = __builtin_amdgcn_mfma_f32_16x16x32_bf16(ah, nf.h, accY[t], 0, 0, 0);
        }

        uint4 su[4];
        #pragma unroll
        for (int t = 0; t < 4; ++t) su[t] = *(const uint4*)(sp + t * 128);
        sp += 2048;

        // s-phase: X += B*s ; Y += G*s
        #pragma unroll
        for (int t = 0; t < 4; ++t) {
            FragU sf;
            sf.u = su[t];
            accX[t] = __builtin_amdgcn_mfma_f32_16x16x32_bf16(ah, sf.h, accX[t], 0, 0, 0);
            accY[t] = __builtin_amdgcn_mfma_f32_16x16x32_bf16(ag, sf.h, accY[t], 0, 0, 0);
        }

        if (it < 7) { g0 = ng0; g1 = ng1; h0 = nh0; h1 = nh1; }
    }

    // cross-wave reduction, two phases to halve LDS.
    // C/D layout: col(b)=lane&15, row(m)=quad*4+reg
    if (wave >= 8) {
        #pragma unroll
        for (int t = 0; t < 4; ++t) {
            #pragma unroll
            for (int r = 0; r < 4; ++r) {
                red[0][wave - 8][(quad << 2) + r][(t << 4) + n] = accX[t][r];
                red[1][wave - 8][(quad << 2) + r][(t << 4) + n] = accY[t][r];
            }
        }
    }
    __syncthreads();
    if (wave < 8) {
        #pragma unroll
        for (int t = 0; t < 4; ++t) {
            #pragma unroll
            for (int r = 0; r < 4; ++r) {
                red[0][wave][(quad << 2) + r][(t << 4) + n] += accX[t][r];
                red[1][wave][(quad << 2) + r][(t << 4) + n] += accY[t][r];
            }
        }
    }
    __syncthreads();

    // 1024 outputs (m,b) per workgroup; 1024 threads -> 1 each; fused epilogue
    {
        int bb = tid >> 4;
        int m = tid & 15;
        float X = 0.f, Y = 0.f;
        #pragma unroll
        for (int w = 0; w < 8; ++w) {
            X += red[0][w][m][bb];
            Y += red[1][w][m][bb];
        }
        size_t off = (size_t)bb * N_DIM + i0 + m;
        float c = c_f[off], s = s_f[off];
        out[off] = c * X + s * Y - P_in[off];                          // res_P
        out[(size_t)B_DIM * N_DIM + off] = s * X - c * Y - Q_in[off];  // res_Q
    }
}

extern "C" void kernel_launch(void* const* d_in, const int* in_sizes, int n_in,
                              void* d_out, int out_size, void* d_ws, size_t ws_size,
                              hipStream_t stream) {
    const float* Vmag = (const float*)d_in[0];
    const float* Vang = (const float*)d_in[1];
    const float* P_in = (const float*)d_in[2];
    const float* Q_in = (const float*)d_in[3];
    const float* G    = (const float*)d_in[4];
    const float* Bm   = (const float*)d_in[5];
    float* out = (float*)d_out;

    char* ws = (char*)d_ws;
    unsigned short* c_pk = (unsigned short*)(ws);                    // 512 KB
    unsigned short* s_pk = (unsigned short*)(ws + (512u << 10));     // 512 KB
    float* c_f = (float*)(ws + (1u << 20));                          // 1 MB
    float* s_f = (float*)(ws + (2u << 20));                          // 1 MB

    hipLaunchKernelGGL(pf_prep, dim3((B_DIM * N_DIM) / 256), dim3(256), 0, stream,
                       Vmag, Vang, c_pk, s_pk, c_f, s_f);
    hipLaunchKernelGGL(pf_gemm, dim3(N_DIM / 16), dim3(1024), 0, stream,
                       G, Bm, c_pk, s_pk, c_f, s_f, P_in, Q_in, out);
}

// Round 3
// 163.727 us; speedup vs baseline: 1.0497x; 1.0497x over previous
//
#include <hip/hip_runtime.h>
#include <stdint.h>

#define N_DIM 4096
#define B_DIM 64

typedef __bf16 bf16x8 __attribute__((ext_vector_type(8)));
typedef float floatx4 __attribute__((ext_vector_type(4)));

union FragU { uint4 u; bf16x8 h; };

#define AS1 __attribute__((address_space(1)))
#define AS3 __attribute__((address_space(3)))

__device__ __forceinline__ void gll16(const float* gp, float* lp) {
    // each lane: 16B from gp (per-lane) -> LDS uniform base lp + lane*16
    __builtin_amdgcn_global_load_lds((const AS1 void*)(const void*)gp,
                                     (AS3 void*)(void*)lp, 16, 0, 0);
}

__device__ __forceinline__ unsigned short f2bf_rne(float f) {
    unsigned int u = __float_as_uint(f);
    u += 0x7fffu + ((u >> 16) & 1u);
    return (unsigned short)(u >> 16);
}

// c = Vmag*cos(ang), s = Vmag*sin(ang).
// fp32 copies in natural [b][j] layout (epilogue), bf16 copies packed in MFMA
// B-fragment order: idx = ((j>>3)*64 + b)*8 + (j&7)
__global__ __launch_bounds__(256) void pf_prep(
        const float* __restrict__ Vmag, const float* __restrict__ Vang,
        unsigned short* __restrict__ c_pk, unsigned short* __restrict__ s_pk,
        float* __restrict__ c_f, float* __restrict__ s_f) {
    int idx = blockIdx.x * 256 + threadIdx.x;   // = b*4096 + j
    int b = idx >> 12;
    int j = idx & 4095;
    float sv, cv;
    sincosf(Vang[idx], &sv, &cv);
    float v = Vmag[idx];
    float c = v * cv;
    float s = v * sv;
    c_f[idx] = c;
    s_f[idx] = s;
    int p = (((j >> 3) << 6) + b) * 8 + (j & 7);
    c_pk[p] = f2bf_rne(c);
    s_pk[p] = f2bf_rne(s);
}

// Block = 16 rows of G/B, 16 waves. K processed in 8 chunks of 512, double-
// buffered LDS staging via global_load_lds (coalesced 1KB per instr per wave:
// wave w stages row w's chunk). Wave w computes K-step [w*32,+32) of each
// chunk. X = G*c + B*s ; Y = G*s - B*c (-c via sign-bit XOR).
// ROWF = 516: row stride in floats (pad 16B, keeps b128 alignment; gll never
// crosses a row within one instruction so padding is safe).
#define ROWF 516
#define MATF (16 * ROWF)        // one matrix tile buffer: 8256 floats
#define BUFF (2 * MATF)         // G+B for one buffer: 16512 floats
__global__ __launch_bounds__(1024, 4) void pf_gemm(
        const float* __restrict__ G, const float* __restrict__ Bm,
        const unsigned short* __restrict__ c_pk, const unsigned short* __restrict__ s_pk,
        const float* __restrict__ c_f, const float* __restrict__ s_f,
        const float* __restrict__ P_in, const float* __restrict__ Q_in,
        float* __restrict__ out) {
    __shared__ __align__(16) float lds_f[2 * BUFF];   // 33024 floats = 129 KB
    const int tid = threadIdx.x;
    const int wave = tid >> 6;        // 0..15
    const int lane = tid & 63;
    const int n = lane & 15;          // A: row m ; B: col b
    const int quad = lane >> 4;       // k-subgroup of 8
    const int i0 = blockIdx.x << 4;   // 16 rows per block

    // staging: wave w owns row i0+w; per chunk 2x 1KB instr per matrix
    const float* gsrc = G  + (size_t)(i0 + wave) * N_DIM + lane * 4;
    const float* bsrc = Bm + (size_t)(i0 + wave) * N_DIM + lane * 4;
    const int stg = wave * ROWF;      // lds row base (floats), + buf*BUFF (+MATF for B)

    // compute-side A-frag base: row n, k-offset wave*32 + quad*8
    const int aoff = n * ROWF + wave * 32 + quad * 8;

    // c/s fragment pointers: k-group = chunk*64 + wave*4 + quad
    const unsigned short* cp = c_pk + ((size_t)(((wave << 2) + quad) << 6) + n) * 8;
    const unsigned short* sp = s_pk + ((size_t)(((wave << 2) + quad) << 6) + n) * 8;

    floatx4 accX[4], accY[4];
    #pragma unroll
    for (int t = 0; t < 4; ++t) {
        accX[t] = (floatx4){0.f, 0.f, 0.f, 0.f};
        accY[t] = (floatx4){0.f, 0.f, 0.f, 0.f};
    }

    // prologue: stage chunk 0 into buffer 0
    gll16(gsrc,       lds_f + stg);
    gll16(gsrc + 256, lds_f + stg + 256);
    gll16(bsrc,       lds_f + MATF + stg);
    gll16(bsrc + 256, lds_f + MATF + stg + 256);

    #pragma unroll 2
    for (int c = 0; c < 8; ++c) {
        const int buf = (c & 1) * BUFF;
        __syncthreads();              // drains vmcnt: chunk c is in LDS for all waves

        if (c < 7) {                  // stage chunk c+1 into other buffer (in flight
            const int nb = ((c + 1) & 1) * BUFF;      //  across the whole compute)
            const float* gs = gsrc + (c + 1) * 512;
            const float* bs = bsrc + (c + 1) * 512;
            gll16(gs,       lds_f + nb + stg);
            gll16(gs + 256, lds_f + nb + stg + 256);
            gll16(bs,       lds_f + nb + MATF + stg);
            gll16(bs + 256, lds_f + nb + MATF + stg + 256);
        }

        // A fragments from LDS (fp32 -> bf16)
        const float* ga = lds_f + buf + aoff;
        const float* ba = lds_f + buf + MATF + aoff;
        float4 g0 = *(const float4*)ga;
        float4 g1 = *(const float4*)(ga + 4);
        float4 h0 = *(const float4*)ba;
        float4 h1 = *(const float4*)(ba + 4);
        bf16x8 ag, ah;
        ag[0] = (__bf16)g0.x; ag[1] = (__bf16)g0.y; ag[2] = (__bf16)g0.z; ag[3] = (__bf16)g0.w;
        ag[4] = (__bf16)g1.x; ag[5] = (__bf16)g1.y; ag[6] = (__bf16)g1.z; ag[7] = (__bf16)g1.w;
        ah[0] = (__bf16)h0.x; ah[1] = (__bf16)h0.y; ah[2] = (__bf16)h0.z; ah[3] = (__bf16)h0.w;
        ah[4] = (__bf16)h1.x; ah[5] = (__bf16)h1.y; ah[6] = (__bf16)h1.z; ah[7] = (__bf16)h1.w;

        // c-phase: X += G*c ; Y += B*(-c)
        uint4 cu[4];
        #pragma unroll
        for (int t = 0; t < 4; ++t) cu[t] = *(const uint4*)(cp + (size_t)c * 32768 + t * 128);
        #pragma unroll
        for (int t = 0; t < 4; ++t) {
            FragU cf, nf;
            cf.u = cu[t];
            nf.u.x = cu[t].x ^ 0x80008000u;
            nf.u.y = cu[t].y ^ 0x80008000u;
            nf.u.z = cu[t].z ^ 0x80008000u;
            nf.u.w = cu[t].w ^ 0x80008000u;
            accX[t] = __builtin_amdgcn_mfma_f32_16x16x32_bf16(ag, cf.h, accX[t], 0, 0, 0);
            accY[t] = __builtin_amdgcn_mfma_f32_16x16x32_bf16(ah, nf.h, accY[t], 0, 0, 0);
        }

        // s-phase: X += B*s ; Y += G*s
        uint4 su[4];
        #pragma unroll
        for (int t = 0; t < 4; ++t) su[t] = *(const uint4*)(sp + (size_t)c * 32768 + t * 128);
        #pragma unroll
        for (int t = 0; t < 4; ++t) {
            FragU sf;
            sf.u = su[t];
            accX[t] = __builtin_amdgcn_mfma_f32_16x16x32_bf16(ah, sf.h, accX[t], 0, 0, 0);
            accY[t] = __builtin_amdgcn_mfma_f32_16x16x32_bf16(ag, sf.h, accY[t], 0, 0, 0);
        }
    }

    // cross-wave reduction in LDS aliased over the staging buffers.
    // C/D layout: col(b)=lane&15, row(m)=quad*4+reg
    float* red = lds_f;   // [2][8][16][66] floats = 16896 <= 33024
    #define RED(x, wp, m, b) red[(((x) * 8 + (wp)) * 16 + (m)) * 66 + (b)]
    __syncthreads();      // all LDS frag reads of last chunk done before overwrite
    if (wave >= 8) {
        #pragma unroll
        for (int t = 0; t < 4; ++t)
            #pragma unroll
            for (int r = 0; r < 4; ++r) {
                RED(0, wave - 8, (quad << 2) + r, (t << 4) + n) = accX[t][r];
                RED(1, wave - 8, (quad << 2) + r, (t << 4) + n) = accY[t][r];
            }
    }
    __syncthreads();
    if (wave < 8) {
        #pragma unroll
        for (int t = 0; t < 4; ++t)
            #pragma unroll
            for (int r = 0; r < 4; ++r) {
                RED(0, wave, (quad << 2) + r, (t << 4) + n) += accX[t][r];
                RED(1, wave, (quad << 2) + r, (t << 4) + n) += accY[t][r];
            }
    }
    __syncthreads();

    // 1024 outputs (m,b); 1024 threads -> 1 each; fused epilogue
    {
        int bb = tid >> 4;
        int m = tid & 15;
        float X = 0.f, Y = 0.f;
        #pragma unroll
        for (int w = 0; w < 8; ++w) {
            X += RED(0, w, m, bb);
            Y += RED(1, w, m, bb);
        }
        size_t off = (size_t)bb * N_DIM + i0 + m;
        float c = c_f[off], s = s_f[off];
        out[off] = c * X + s * Y - P_in[off];                          // res_P
        out[(size_t)B_DIM * N_DIM + off] = s * X - c * Y - Q_in[off];  // res_Q
    }
}

extern "C" void kernel_launch(void* const* d_in, const int* in_sizes, int n_in,
                              void* d_out, int out_size, void* d_ws, size_t ws_size,
                              hipStream_t stream) {
    const float* Vmag = (const float*)d_in[0];
    const float* Vang = (const float*)d_in[1];
    const float* P_in = (const float*)d_in[2];
    const float* Q_in = (const float*)d_in[3];
    const float* G    = (const float*)d_in[4];
    const float* Bm   = (const float*)d_in[5];
    float* out = (float*)d_out;

    char* ws = (char*)d_ws;
    unsigned short* c_pk = (unsigned short*)(ws);                    // 512 KB
    unsigned short* s_pk = (unsigned short*)(ws + (512u << 10));     // 512 KB
    float* c_f = (float*)(ws + (1u << 20));                          // 1 MB
    float* s_f = (float*)(ws + (2u << 20));                          // 1 MB

    hipLaunchKernelGGL(pf_prep, dim3((B_DIM * N_DIM) / 256), dim3(256), 0, stream,
                       Vmag, Vang, c_pk, s_pk, c_f, s_f);
    hipLaunchKernelGGL(pf_gemm, dim3(N_DIM / 16), dim3(1024), 0, stream,
                       G, Bm, c_pk, s_pk, c_f, s_f, P_in, Q_in, out);
}